// Round 1
// 620.295 us; speedup vs baseline: 1.1654x; 1.1654x over previous
//
#include <hip/hip_runtime.h>
#include <hip/hip_bf16.h>
#include <stdint.h>

// Problem constants: x[4096,4096] f32, qweight[4096,1376] i32,
// scales[32,11008] f32, qzeros[32,1376] i32, group_size=128. out[4096,11008] f32.
#define M_DIM 4096
#define K_DIM 4096
#define N_DIM 11008
#define OPACK (N_DIM / 8)   // 1376
#define GSZ   128

// GEMM geometry: 256x256 block tile, BK=64 (2 ksubs of 32), 8 waves (2M x 4N),
// 512 threads, 8-phase K-loop, 2 K-tiles per iteration.
#define NIT 32              // K / 128

typedef __attribute__((ext_vector_type(8))) short short8;        // 8 bf16 (MFMA A/B frag)
typedef __attribute__((ext_vector_type(4))) float floatx4;       // MFMA C/D frag
typedef __attribute__((ext_vector_type(4))) unsigned int uintx4; // 16B vector

static __device__ __forceinline__ unsigned short f32_to_bf16_rne(float f) {
    union { float f; unsigned int u; } c; c.f = f;
    unsigned int u = c.u;
    u += 0x7fffu + ((u >> 16) & 1u);   // round-to-nearest-even (no NaN inputs here)
    return (unsigned short)(u >> 16);
}

// async global->LDS, 16B per lane. LDS dest must be wave-uniform base + lane*16.
static __device__ __forceinline__ void load16_lds(const void* gptr, void* lptr) {
    __builtin_amdgcn_global_load_lds(
        (__attribute__((address_space(1))) void*)gptr,
        (__attribute__((address_space(3))) void*)lptr,
        16, 0, 0);
}

// ---------------------------------------------------------------------------
// Kernel 1: x fp32 [M][K] -> bf16 (row-major, same layout)
// ---------------------------------------------------------------------------
__global__ __launch_bounds__(256)
void convert_x_kernel(const float* __restrict__ x, unsigned short* __restrict__ xb) {
    const int idx = (blockIdx.x * 256 + threadIdx.x) * 8;
    floatx4 v0 = *(const floatx4*)(x + idx);
    floatx4 v1 = *(const floatx4*)(x + idx + 4);
    unsigned short r[8];
#pragma unroll
    for (int i = 0; i < 4; i++) {
        r[i]     = f32_to_bf16_rne(v0[i]);
        r[4 + i] = f32_to_bf16_rne(v1[i]);
    }
    *(uintx4*)(xb + idx) = *(const uintx4*)r;
}

// ---------------------------------------------------------------------------
// Kernel 2: dequant int4 -> bf16, TRANSPOSED: Wt[o][i] = (nib(qw[i][o]) - nib(qz[g][o])) * s[g][o]
// ROUND 4: one thread covers 64 consecutive i -> one FULL 128B cacheline per
// thread (was 64B: two different blockIdx.y blocks split each 128B TCC line ->
// 2x write amplification). i0 multiple of 64 stays within one scale group (128).
// ---------------------------------------------------------------------------
__global__ __launch_bounds__(256)
void dequant_kernel(const int* __restrict__ qweight, const float* __restrict__ scales,
                    const int* __restrict__ qzeros, unsigned short* __restrict__ Wt) {
    const int o  = blockIdx.x * 256 + threadIdx.x;   // [0, 11008)
    const int i0 = blockIdx.y * 64;                  // [0, 4096)
    const int g  = i0 >> 7;
    const int op = o >> 3;
    const int sh = (o & 7) * 4;
    const int z  = (qzeros[g * OPACK + op] >> sh) & 15;
    const float s = scales[g * N_DIM + o];
    unsigned short buf[64];
#pragma unroll
    for (int k = 0; k < 64; k++) {
        const int q   = qweight[(i0 + k) * OPACK + op];
        const float w = (float)(((q >> sh) & 15) - z) * s;
        buf[k] = f32_to_bf16_rne(w);
    }
    uintx4* dst = (uintx4*)(Wt + (size_t)o * K_DIM + i0);
    const uintx4* src = (const uintx4*)buf;
#pragma unroll
    for (int t = 0; t < 8; t++) dst[t] = src[t];
}

// ---------------------------------------------------------------------------
// Kernel 3: C[M][N] f32 = Xb[M][K] (bf16) @ Wt[N][K]^T (bf16)
// ROUND 4: 256x256 8-phase counted-vmcnt template (guide S5, m201-class).
//   - 128 KiB LDS: per matrix 4 regions of 16KB, region r = (buf*2 + ksub),
//     holding [256 rows][32 k] bf16. One region = one stage unit
//     (2 x global_load_lds dwordx4 per thread).
//   - Phase = (buf, ksub, mhalf): 16 MFMA; B-frags register-reused across the
//     h0/h1 pair (so phases issue 8 or 4 ds_read_b128).
//   - Staging: 1 unit/phase, ~6-phase lead. vmcnt(6) at phases 4 and 8 only
//     (3 units in flight); vmcnt(0) variants only on the last iteration.
//     Schedule verified on paper: every stage is issued >=1 barrier after its
//     region's last read retired (reads retire at that phase's lgkmcnt(0));
//     every read's unit is forced-landed by the preceding vmcnt(6).
//   - T2 swizzle: LDS chunk c XOR (row>>1)&3, applied by PRE-SWIZZLING the
//     per-lane global source address (LDS dest stays linear for gload_lds);
//     read side folds to per-lane constant kcs = (lane>>4)^((lane>>1)&3).
//     Kills the 8-way ds_read_b128 bank conflict (4.5e7 -> ~0).
//   - T5: s_setprio(1) around each 16-MFMA cluster.
//   - T1: XCD swizzle, 688 blocks = 8 XCDs x 86, m-fast (16 consecutive blocks
//     share one 2MB B panel in the XCD's L2).
// ---------------------------------------------------------------------------

#define STAGE_A(KB, RG) do {                                   \
    const char* g_ = ApS + (size_t)(KB) * 64;                  \
    char* l_ = (char*)lds_a[RG] + tid * 16;                    \
    load16_lds(g_, l_);                                        \
    load16_lds(g_ + (1u << 20), l_ + 8192);                    \
} while (0)

#define STAGE_B(KB, RG) do {                                   \
    const char* g_ = BpS + (size_t)(KB) * 64;                  \
    char* l_ = (char*)lds_b[RG] + tid * 16;                    \
    load16_lds(g_, l_);                                        \
    load16_lds(g_ + (1u << 20), l_ + 8192);                    \
} while (0)

#define VM_NONE ((void)0)
#define VM_TILE do {                                                        \
    if (more) { asm volatile("s_waitcnt vmcnt(6)" ::: "memory"); }          \
    else      { asm volatile("s_waitcnt vmcnt(0)" ::: "memory"); }          \
} while (0)

// one phase: {ds-read frags | stage 1 unit | [vmcnt] | barrier | lgkm(0) |
//             setprio(1) 16xMFMA setprio(0) | barrier}
#define PHASE(B_, KS_, H_, VMW_, ...) do {                                           \
    const short* Ar_ = &lds_a[(B_) * 2 + (KS_)][a_off + (H_) * 2048];                \
    short8 av_[4];                                                                   \
    _Pragma("unroll")                                                                \
    for (int f_ = 0; f_ < 4; ++f_) av_[f_] = *(const short8*)(Ar_ + f_ * 512);       \
    if ((H_) == 0) {                                                                 \
        const short* Br_ = &lds_b[(B_) * 2 + (KS_)][b_off];                          \
        _Pragma("unroll")                                                            \
        for (int n_ = 0; n_ < 4; ++n_) bv[n_] = *(const short8*)(Br_ + n_ * 512);    \
    }                                                                                \
    __VA_ARGS__;                                                                     \
    VMW_;                                                                            \
    __builtin_amdgcn_s_barrier();                                                    \
    asm volatile("s_waitcnt lgkmcnt(0)" ::: "memory");                               \
    __builtin_amdgcn_sched_barrier(0);                                               \
    __builtin_amdgcn_s_setprio(1);                                                   \
    _Pragma("unroll")                                                                \
    for (int f_ = 0; f_ < 4; ++f_)                                                   \
        _Pragma("unroll")                                                            \
        for (int n_ = 0; n_ < 4; ++n_)                                               \
            acc[(H_) * 4 + f_][n_] = __builtin_amdgcn_mfma_f32_16x16x32_bf16(        \
                av_[f_], bv[n_], acc[(H_) * 4 + f_][n_], 0, 0, 0);                   \
    __builtin_amdgcn_s_setprio(0);                                                   \
    __builtin_amdgcn_s_barrier();                                                    \
} while (0)

__global__ __launch_bounds__(512, 2)
void gemm_kernel(const unsigned short* __restrict__ X,   // [M][K] bf16
                 const unsigned short* __restrict__ Wt,  // [N][K] bf16
                 float* __restrict__ C) {                // [M][N] f32
    __shared__ __align__(16) short lds_a[4][8192];   // 4 x 16KB regions (buf*2+ksub)
    __shared__ __align__(16) short lds_b[4][8192];   // total 128 KiB

    const int tid  = threadIdx.x;
    const int wave = tid >> 6;
    const int lane = tid & 63;
    const int wm   = wave >> 2;        // 0..1  (M)
    const int wn   = wave & 3;         // 0..3  (N)

    // XCD swizzle: 688 blocks = 8 * 86; m-fast within each XCD chunk.
    const int pid    = blockIdx.x;
    const int L      = (pid & 7) * 86 + (pid >> 3);
    const int m_tile = L & 15;          // [0,16)
    const int n_tile = L >> 4;          // [0,43)
    const int m0 = m_tile * 256;
    const int n0 = n_tile * 256;

    // staging source: thread t fills LDS region rows (t>>2) and (t>>2)+128,
    // chunk position t&3. Pre-swizzled global chunk: cl = (t&3) ^ ((row>>1)&3).
    const int row_l = tid >> 2;
    const int cl    = (tid & 3) ^ ((tid >> 3) & 3);
    const char* ApS = (const char*)X  + ((size_t)(m0 + row_l) << 13) + (cl << 4);
    const char* BpS = (const char*)Wt + ((size_t)(n0 + row_l) << 13) + (cl << 4);

    // frag read offsets (in shorts); swizzled chunk index is per-lane constant.
    const int l15 = lane & 15;
    const int kcs = (lane >> 4) ^ ((lane >> 1) & 3);
    const int a_off = (wm * 128 + l15) * 32 + kcs * 8;
    const int b_off = (wn * 64  + l15) * 32 + kcs * 8;

    floatx4 acc[8][4] = {};
    short8 bv[4];

    // prologue: stage tile0 (B-k0,A-k0,B-k1,A-k1) + tile1 (B-k0,A-k0,B-k1).
    // vmcnt(6) -> first 4 units (tile 0) landed; 3 units in flight.
    STAGE_B(0, 0); STAGE_A(0, 0);
    STAGE_B(1, 1); STAGE_A(1, 1);
    STAGE_B(2, 2); STAGE_A(2, 2);
    STAGE_B(3, 3);
    asm volatile("s_waitcnt vmcnt(6)" ::: "memory");
    __builtin_amdgcn_s_barrier();

#pragma unroll 1
    for (int i = 0; i < NIT; ++i) {
        const int  kb4  = 4 * i;
        const bool more = (i + 1 < NIT);
        // tiles: buf0 = tile 2i (p1-p4), buf1 = tile 2i+1 (p5-p8)
        // stages: p1: A-k1(2i+1)->A3 | p2..p5: tile 2i+2 -> regions 0,0,1,1
        //         p6..p8: tile 2i+3 -> regions 2,2,3
        PHASE(0, 0, 0, VM_NONE, STAGE_A(kb4 + 3, 3));
        PHASE(0, 0, 1, VM_NONE, if (more) STAGE_B(kb4 + 4, 0));
        PHASE(0, 1, 0, VM_NONE, if (more) STAGE_A(kb4 + 4, 0));
        PHASE(0, 1, 1, VM_TILE, if (more) STAGE_B(kb4 + 5, 1));
        PHASE(1, 0, 0, VM_NONE, if (more) STAGE_A(kb4 + 5, 1));
        PHASE(1, 0, 1, VM_NONE, if (more) STAGE_B(kb4 + 6, 2));
        PHASE(1, 1, 0, VM_NONE, if (more) STAGE_A(kb4 + 6, 2));
        PHASE(1, 1, 1, VM_TILE, if (more) STAGE_B(kb4 + 7, 3));
    }

    // epilogue: C/D layout col=lane&15, row=(lane>>4)*4+reg  [verified m89/m91]
    // nontemporal: C is write-once, never re-read.
    const int crow = (lane >> 4) * 4;
#pragma unroll
    for (int f = 0; f < 8; ++f) {
#pragma unroll
        for (int n = 0; n < 4; ++n) {
            float* Cp = C + (size_t)(m0 + wm * 128 + f * 16 + crow) * N_DIM
                          + (n0 + wn * 64 + n * 16 + l15);
#pragma unroll
            for (int r = 0; r < 4; ++r)
                __builtin_nontemporal_store(acc[f][n][r], Cp + (size_t)r * N_DIM);
        }
    }
}

// ---------------------------------------------------------------------------
extern "C" void kernel_launch(void* const* d_in, const int* in_sizes, int n_in,
                              void* d_out, int out_size, void* d_ws, size_t ws_size,
                              hipStream_t stream) {
    const float* x       = (const float*)d_in[0];
    const int*   qweight = (const int*)d_in[1];
    const float* scales  = (const float*)d_in[2];
    const int*   qzeros  = (const int*)d_in[3];
    // d_in[4] = group_size scalar (always 128 per setup_inputs) -- baked in.
    float* out = (float*)d_out;

    // ws layout: Xb bf16 [M][K] (33.5 MB) | Wt bf16 [N][K] (90.2 MB)
    unsigned short* Xb = (unsigned short*)d_ws;
    unsigned short* Wt = (unsigned short*)((char*)d_ws + (size_t)M_DIM * K_DIM * 2);

    convert_x_kernel<<<(M_DIM * K_DIM) / (256 * 8), 256, 0, stream>>>(x, Xb);
    dequant_kernel<<<dim3(N_DIM / 256, K_DIM / 64), 256, 0, stream>>>(qweight, scales, qzeros, Wt);
    gemm_kernel<<<(M_DIM / 256) * (N_DIM / 256), 512, 0, stream>>>(Xb, Wt, out);
}

// Round 2
// 616.079 us; speedup vs baseline: 1.1734x; 1.0068x over previous
//
#include <hip/hip_runtime.h>
#include <hip/hip_bf16.h>
#include <stdint.h>

// Problem constants: x[4096,4096] f32, qweight[4096,1376] i32,
// scales[32,11008] f32, qzeros[32,1376] i32, group_size=128. out[4096,11008] f32.
#define M_DIM 4096
#define K_DIM 4096
#define N_DIM 11008
#define OPACK (N_DIM / 8)   // 1376
#define GSZ   128

// GEMM geometry: 256x256 block tile, BK=64 (2 ksubs of 32), 8 waves (2M x 4N),
// 512 threads, 8-phase K-loop, 2 K-tiles per iteration.
#define NIT 32              // K / 128

typedef __attribute__((ext_vector_type(8))) short short8;        // 8 bf16 (MFMA A/B frag)
typedef __attribute__((ext_vector_type(4))) float floatx4;       // MFMA C/D frag
typedef __attribute__((ext_vector_type(4))) unsigned int uintx4; // 16B vector

static __device__ __forceinline__ unsigned short f32_to_bf16_rne(float f) {
    union { float f; unsigned int u; } c; c.f = f;
    unsigned int u = c.u;
    u += 0x7fffu + ((u >> 16) & 1u);   // round-to-nearest-even (no NaN inputs here)
    return (unsigned short)(u >> 16);
}

// async global->LDS, 16B per lane. LDS dest must be wave-uniform base + lane*16.
static __device__ __forceinline__ void load16_lds(const void* gptr, void* lptr) {
    __builtin_amdgcn_global_load_lds(
        (__attribute__((address_space(1))) void*)gptr,
        (__attribute__((address_space(3))) void*)lptr,
        16, 0, 0);
}

// ---------------------------------------------------------------------------
// Kernel 1: x fp32 [M][K] -> bf16 (row-major, same layout)
// ---------------------------------------------------------------------------
__global__ __launch_bounds__(256)
void convert_x_kernel(const float* __restrict__ x, unsigned short* __restrict__ xb) {
    const int idx = (blockIdx.x * 256 + threadIdx.x) * 8;
    floatx4 v0 = *(const floatx4*)(x + idx);
    floatx4 v1 = *(const floatx4*)(x + idx + 4);
    unsigned short r[8];
#pragma unroll
    for (int i = 0; i < 4; i++) {
        r[i]     = f32_to_bf16_rne(v0[i]);
        r[4 + i] = f32_to_bf16_rne(v1[i]);
    }
    *(uintx4*)(xb + idx) = *(const uintx4*)r;
}

// ---------------------------------------------------------------------------
// Kernel 2: dequant int4 -> bf16, TRANSPOSED: Wt[o][i] = (nib(qw[i][o]) - nib(qz[g][o])) * s[g][o]
// One thread: fixed o, 64 consecutive i -> one FULL 128B cacheline per thread.
// ---------------------------------------------------------------------------
__global__ __launch_bounds__(256)
void dequant_kernel(const int* __restrict__ qweight, const float* __restrict__ scales,
                    const int* __restrict__ qzeros, unsigned short* __restrict__ Wt) {
    const int o  = blockIdx.x * 256 + threadIdx.x;   // [0, 11008)
    const int i0 = blockIdx.y * 64;                  // [0, 4096)
    const int g  = i0 >> 7;
    const int op = o >> 3;
    const int sh = (o & 7) * 4;
    const int z  = (qzeros[g * OPACK + op] >> sh) & 15;
    const float s = scales[g * N_DIM + o];
    unsigned short buf[64];
#pragma unroll
    for (int k = 0; k < 64; k++) {
        const int q   = qweight[(i0 + k) * OPACK + op];
        const float w = (float)(((q >> sh) & 15) - z) * s;
        buf[k] = f32_to_bf16_rne(w);
    }
    uintx4* dst = (uintx4*)(Wt + (size_t)o * K_DIM + i0);
    const uintx4* src = (const uintx4*)buf;
#pragma unroll
    for (int t = 0; t < 8; t++) dst[t] = src[t];
}

// ---------------------------------------------------------------------------
// Kernel 3: C[M][N] f32 = Xb[M][K] (bf16) @ Wt[N][K]^T (bf16)
// ROUND 5: pipelined-read single-barrier 8-phase schedule.
//   Phase P: { MFMA(P) | sched_barrier | [vmcnt(4)] | ds_reads(P+1) | stage | s_barrier }
//   - Fragment ds_reads for phase P+1 issue right after MFMA(P)'s issue slots,
//     so their ~120-200cy latency hides under the MFMA pipe drain + barrier.
//     Round-4 measured MfmaUtil 42.7% == 155cy MFMA / (155 + exposed ds_read+2bar);
//     this removes the exposed latency and halves barrier count (1/phase).
//   - Wait ledger (paper-verified): stages +2 loads/phase at slots
//     p1:A3 p2:B0' p3:A0' p4:B1' p5:A1' p6:B2' p7:A2' p8:B3'.
//     vmcnt(4) at p2/p4/p6/p8 lands exactly the unit staged 3 phases earlier:
//       W(p2)->A2(prev p7), W(p4)->A3(p1), W(p6)->A0'(p3), W(p8)->A1'(p5).
//     Every R(P) [issued P-1] is covered by a wait >=1 full phase + barrier
//     before its issue; every WAR has >=1 barrier between last-read retire
//     (before MFMA(P+1) completes) and the overwriting stage.
//     Final iter: W(p4)=vmcnt(0), W(p6)/W(p8)/p8-reads skipped.
//   - T2 swizzle, T5 setprio, T1 XCD swizzle retained from round 4
//     (bank conflicts measured 0).
// ---------------------------------------------------------------------------

#define STAGE_A(KB, RG) do {                                   \
    const char* g_ = ApS + (size_t)(KB) * 64;                  \
    char* l_ = (char*)lds_a[RG] + tid * 16;                    \
    load16_lds(g_, l_);                                        \
    load16_lds(g_ + (1u << 20), l_ + 8192);                    \
} while (0)

#define STAGE_B(KB, RG) do {                                   \
    const char* g_ = BpS + (size_t)(KB) * 64;                  \
    char* l_ = (char*)lds_b[RG] + tid * 16;                    \
    load16_lds(g_, l_);                                        \
    load16_lds(g_ + (1u << 20), l_ + 8192);                    \
} while (0)

#define VM4 asm volatile("s_waitcnt vmcnt(4)" ::: "memory")
#define VM0 asm volatile("s_waitcnt vmcnt(0)" ::: "memory")
#define VM_NONE ((void)0)

#define LDA_FRAGS(RG_, RH_) do {                                                  \
    const short* Ar_ = &lds_a[RG_][a_off + (RH_) * 2048];                         \
    _Pragma("unroll")                                                             \
    for (int f_ = 0; f_ < 4; ++f_) av[f_] = *(const short8*)(Ar_ + f_ * 512);     \
} while (0)

#define LDB_FRAGS(RG_) do {                                                       \
    const short* Br_ = &lds_b[RG_][b_off];                                        \
    _Pragma("unroll")                                                             \
    for (int n_ = 0; n_ < 4; ++n_) bv[n_] = *(const short8*)(Br_ + n_ * 512);     \
} while (0)

// H_: acc m-half for MFMA(P). RG_/RH_/LB_: frag source for phase P+1.
// RDC_: issue next reads? VMW_: vm wait stmt. STG_: stage stmt.
#define PHASE(H_, RG_, RH_, LB_, RDC_, VMW_, STG_) do {                              \
    __builtin_amdgcn_s_setprio(1);                                                   \
    _Pragma("unroll")                                                                \
    for (int f_ = 0; f_ < 4; ++f_)                                                   \
        _Pragma("unroll")                                                            \
        for (int n_ = 0; n_ < 4; ++n_)                                               \
            acc[(H_) * 4 + f_][n_] = __builtin_amdgcn_mfma_f32_16x16x32_bf16(        \
                av[f_], bv[n_], acc[(H_) * 4 + f_][n_], 0, 0, 0);                    \
    __builtin_amdgcn_s_setprio(0);                                                   \
    __builtin_amdgcn_sched_barrier(0);                                               \
    VMW_;                                                                            \
    if (RDC_) { LDA_FRAGS(RG_, RH_); if (LB_) LDB_FRAGS(RG_); }                      \
    STG_;                                                                            \
    asm volatile("s_barrier" ::: "memory");                                          \
} while (0)

__global__ __launch_bounds__(512, 2)
void gemm_kernel(const unsigned short* __restrict__ X,   // [M][K] bf16
                 const unsigned short* __restrict__ Wt,  // [N][K] bf16
                 float* __restrict__ C) {                // [M][N] f32
    __shared__ __align__(16) short lds_a[4][8192];   // 4 x 16KB regions (buf*2+ksub)
    __shared__ __align__(16) short lds_b[4][8192];   // total 128 KiB

    const int tid  = threadIdx.x;
    const int wave = tid >> 6;
    const int lane = tid & 63;
    const int wm   = wave >> 2;        // 0..1  (M)
    const int wn   = wave & 3;         // 0..3  (N)

    // XCD swizzle: 688 blocks = 8 * 86; m-fast within each XCD chunk
    // (16 consecutive blocks share one 2MB Wt panel in the XCD's L2).
    const int pid    = blockIdx.x;
    const int L      = (pid & 7) * 86 + (pid >> 3);
    const int m_tile = L & 15;          // [0,16)
    const int n_tile = L >> 4;          // [0,43)
    const int m0 = m_tile * 256;
    const int n0 = n_tile * 256;

    // staging source: thread t fills LDS region rows (t>>2) and (t>>2)+128,
    // chunk position t&3. Pre-swizzled global chunk: cl = (t&3) ^ ((row>>1)&3).
    const int row_l = tid >> 2;
    const int cl    = (tid & 3) ^ ((tid >> 3) & 3);
    const char* ApS = (const char*)X  + ((size_t)(m0 + row_l) << 13) + (cl << 4);
    const char* BpS = (const char*)Wt + ((size_t)(n0 + row_l) << 13) + (cl << 4);

    // frag read offsets (in shorts); swizzled chunk index is per-lane constant.
    const int l15 = lane & 15;
    const int kcs = (lane >> 4) ^ ((lane >> 1) & 3);
    const int a_off = (wm * 128 + l15) * 32 + kcs * 8;
    const int b_off = (wn * 64  + l15) * 32 + kcs * 8;

    floatx4 acc[8][4] = {};
    short8 av[4], bv[4];

    // prologue: stage tile0 (B0,A0,B1,A1) + tile1 (B2,A2,B3) = 14 loads.
    // vmcnt(6) -> tile0 (8 oldest loads) landed; barrier; issue R(p1).
    STAGE_B(0, 0); STAGE_A(0, 0);
    STAGE_B(1, 1); STAGE_A(1, 1);
    STAGE_B(2, 2); STAGE_A(2, 2);
    STAGE_B(3, 3);
    asm volatile("s_waitcnt vmcnt(6)" ::: "memory");
    asm volatile("s_barrier" ::: "memory");
    LDA_FRAGS(0, 0);
    LDB_FRAGS(0);

#pragma unroll 1
    for (int i = 0; i < NIT; ++i) {
        const int  kb4  = 4 * i;
        const bool more = (i + 1 < NIT);
        // phases (B,KS,H): p1=(0,0,0) p2=(0,0,1) p3=(0,1,0) p4=(0,1,1)
        //                  p5=(1,0,0) p6=(1,0,1) p7=(1,1,0) p8=(1,1,1)
        // reads target phase P+1's region (RG = B*2+KS), B-frags on h0 targets.
        PHASE(0, 0, 1, 0, 1, VM_NONE,                  STAGE_A(kb4 + 3, 3));
        PHASE(1, 1, 0, 1, 1, VM4,                      if (more) STAGE_B(kb4 + 4, 0));
        PHASE(0, 1, 1, 0, 1, VM_NONE,                  if (more) STAGE_A(kb4 + 4, 0));
        PHASE(1, 2, 0, 1, 1, if (more) VM4; else VM0,  if (more) STAGE_B(kb4 + 5, 1));
        PHASE(0, 2, 1, 0, 1, VM_NONE,                  if (more) STAGE_A(kb4 + 5, 1));
        PHASE(1, 3, 0, 1, 1, if (more) VM4,            if (more) STAGE_B(kb4 + 6, 2));
        PHASE(0, 3, 1, 0, 1, VM_NONE,                  if (more) STAGE_A(kb4 + 6, 2));
        PHASE(1, 0, 0, 1, more, if (more) VM4,         if (more) STAGE_B(kb4 + 7, 3));
    }

    // epilogue: C/D layout col=lane&15, row=(lane>>4)*4+reg  [verified m89/m91]
    // nontemporal: C is write-once, never re-read.
    const int crow = (lane >> 4) * 4;
#pragma unroll
    for (int f = 0; f < 8; ++f) {
#pragma unroll
        for (int n = 0; n < 4; ++n) {
            float* Cp = C + (size_t)(m0 + wm * 128 + f * 16 + crow) * N_DIM
                          + (n0 + wn * 64 + n * 16 + l15);
#pragma unroll
            for (int r = 0; r < 4; ++r)
                __builtin_nontemporal_store(acc[f][n][r], Cp + (size_t)r * N_DIM);
        }
    }
}

// ---------------------------------------------------------------------------
extern "C" void kernel_launch(void* const* d_in, const int* in_sizes, int n_in,
                              void* d_out, int out_size, void* d_ws, size_t ws_size,
                              hipStream_t stream) {
    const float* x       = (const float*)d_in[0];
    const int*   qweight = (const int*)d_in[1];
    const float* scales  = (const float*)d_in[2];
    const int*   qzeros  = (const int*)d_in[3];
    // d_in[4] = group_size scalar (always 128 per setup_inputs) -- baked in.
    float* out = (float*)d_out;

    // ws layout: Xb bf16 [M][K] (33.5 MB) | Wt bf16 [N][K] (90.2 MB)
    unsigned short* Xb = (unsigned short*)d_ws;
    unsigned short* Wt = (unsigned short*)((char*)d_ws + (size_t)M_DIM * K_DIM * 2);

    convert_x_kernel<<<(M_DIM * K_DIM) / (256 * 8), 256, 0, stream>>>(x, Xb);
    dequant_kernel<<<dim3(N_DIM / 256, K_DIM / 64), 256, 0, stream>>>(qweight, scales, qzeros, Wt);
    gemm_kernel<<<(M_DIM / 256) * (N_DIM / 256), 512, 0, stream>>>(Xb, Wt, out);
}

// Round 3
// 613.679 us; speedup vs baseline: 1.1780x; 1.0039x over previous
//
#include <hip/hip_runtime.h>
#include <hip/hip_bf16.h>
#include <stdint.h>

// Problem constants: x[4096,4096] f32, qweight[4096,1376] i32,
// scales[32,11008] f32, qzeros[32,1376] i32, group_size=128. out[4096,11008] f32.
#define M_DIM 4096
#define K_DIM 4096
#define N_DIM 11008
#define OPACK (N_DIM / 8)   // 1376
#define GSZ   128

// GEMM geometry: 256x256 block tile, BK=64 (2 ksubs of 32), 8 waves (2M x 4N),
// 512 threads, 8-phase K-loop, 2 K-tiles per iteration.
#define NIT 32              // K / 128

typedef __attribute__((ext_vector_type(8))) short short8;        // 8 bf16 (MFMA A/B frag)
typedef __attribute__((ext_vector_type(4))) float floatx4;       // MFMA C/D frag
typedef __attribute__((ext_vector_type(4))) unsigned int uintx4; // 16B vector

static __device__ __forceinline__ unsigned short f32_to_bf16_rne(float f) {
    union { float f; unsigned int u; } c; c.f = f;
    unsigned int u = c.u;
    u += 0x7fffu + ((u >> 16) & 1u);   // round-to-nearest-even (no NaN inputs here)
    return (unsigned short)(u >> 16);
}

// async global->LDS, 16B per lane. LDS dest must be wave-uniform base + lane*16.
static __device__ __forceinline__ void load16_lds(const void* gptr, void* lptr) {
    __builtin_amdgcn_global_load_lds(
        (__attribute__((address_space(1))) void*)gptr,
        (__attribute__((address_space(3))) void*)lptr,
        16, 0, 0);
}

// ---------------------------------------------------------------------------
// Kernel 1: x fp32 [M][K] -> bf16 (row-major, same layout)
// ---------------------------------------------------------------------------
__global__ __launch_bounds__(256)
void convert_x_kernel(const float* __restrict__ x, unsigned short* __restrict__ xb) {
    const int idx = (blockIdx.x * 256 + threadIdx.x) * 8;
    floatx4 v0 = *(const floatx4*)(x + idx);
    floatx4 v1 = *(const floatx4*)(x + idx + 4);
    unsigned short r[8];
#pragma unroll
    for (int i = 0; i < 4; i++) {
        r[i]     = f32_to_bf16_rne(v0[i]);
        r[4 + i] = f32_to_bf16_rne(v1[i]);
    }
    *(uintx4*)(xb + idx) = *(const uintx4*)r;
}

// ---------------------------------------------------------------------------
// Kernel 2: dequant int4 -> bf16 transposed, Wt[o][i].
// ROUND 6: LDS-staged coalesced writes. Old version: each thread wrote its own
// Wt row -> every wave-store scattered 64 partial 128B lines (8x transaction
// amplification at TCC). New: compute into LDS tile [256 o][64 i] with
// XOR-swizzled 16B chunks (provably even bank load: bank = s*4+d, each s taken
// by exactly 8 lanes = the b128 floor), then write out wave-coalesced:
// each wave-store covers 8 full consecutive 128B lines.
// ---------------------------------------------------------------------------
__global__ __launch_bounds__(256)
void dequant_kernel(const int* __restrict__ qweight, const float* __restrict__ scales,
                    const int* __restrict__ qzeros, unsigned short* __restrict__ Wt) {
    __shared__ __align__(16) unsigned short tile[256][64];   // 32 KB

    const int tid = threadIdx.x;
    const int o0  = blockIdx.x * 256;
    const int i0  = blockIdx.y * 64;                 // one scale group spans >=64 i
    const int o   = o0 + tid;
    const int g   = i0 >> 7;
    const int op  = o >> 3;
    const int sh  = (o & 7) * 4;
    const int z   = (qzeros[g * OPACK + op] >> sh) & 15;
    const float s = scales[g * N_DIM + o];

    unsigned short buf[64];
#pragma unroll
    for (int k = 0; k < 64; k++) {
        const int q   = qweight[(i0 + k) * OPACK + op];
        const float w = (float)(((q >> sh) & 15) - z) * s;
        buf[k] = f32_to_bf16_rne(w);
    }
    // stage into LDS row tid, chunk c stored at slot c ^ (tid&7)
#pragma unroll
    for (int c = 0; c < 8; c++)
        *(uintx4*)&tile[tid][(c ^ (tid & 7)) * 8] = *(const uintx4*)&buf[c * 8];

    __syncthreads();

    // write out: iteration j covers rows (tid>>3) + 32j; lanes 0..7 cover the
    // 8 chunks of one row -> each wave-store = 8 full 128B lines.
    const int c_out = tid & 7;
#pragma unroll
    for (int j = 0; j < 8; j++) {
        const int r = (tid >> 3) + j * 32;
        const uintx4 v = *(const uintx4*)&tile[r][(c_out ^ (r & 7)) * 8];
        *(uintx4*)&Wt[(size_t)(o0 + r) * K_DIM + i0 + c_out * 8] = v;
    }
}

// ---------------------------------------------------------------------------
// Kernel 3: C[M][N] f32 = Xb[M][K] (bf16) @ Wt[N][K]^T (bf16)
// ROUND 6: interleaved-issue phase with ping-pong fragment registers.
//   Round-5 post-mortem: phase time == MFMA pipe time + LDS read time (SUM, not
//   max) because reads were fenced after the MFMA cluster -> pipes serialized
//   (measured 1317 cy/phase ~= 621 MFMA + 576 ds_read + sync; MfmaUtil 44%).
//   Fix: reads(P+1) go to the OTHER register set (av/bv ping-pong) and are
//   issued at phase start with NO sched_barrier, so the scheduler interleaves
//   them into the MFMA(P) issue window -> LDS pipe drains under the MFMA burst.
//   Phase: { [reads(P+1) -> other set] | stage | MFMA(P) | [vmcnt] | barrier }
//   - vmcnt waits moved BEFORE the phase-ending barrier (a per-wave wait only
//     has cross-wave meaning if all waves execute it before barrier release).
//     Ledger: vmcnt(8) at end of p1/p3/p5/p7 => all stages >=5 phases old have
//     landed for the d=5 reads at the following even phase; odd-phase reads
//     (d=6) covered by the wait one phase earlier. Final iter: p3->vmcnt(4),
//     p5->vmcnt(0), p7->skip (p8 reads nothing).
//   - WAR: a region's last reads lgkm-retire before that phase's MFMA issues;
//     the overwriting stage is >=1 barrier later. Async LDS-writes land after
//     issue -> safe.
//   - T2 swizzle (conflicts measured 0), T5 setprio, T1 XCD swizzle retained.
//   - VGPR: acc 128 + frags 64 + addr ~25 < 256 -> still 2 waves/SIMD.
// ---------------------------------------------------------------------------

#define STAGE_A(KB, RG) do {                                   \
    const char* g_ = ApS + (size_t)(KB) * 64;                  \
    char* l_ = (char*)lds_a[RG] + tid * 16;                    \
    load16_lds(g_, l_);                                        \
    load16_lds(g_ + (1u << 20), l_ + 8192);                    \
} while (0)

#define STAGE_B(KB, RG) do {                                   \
    const char* g_ = BpS + (size_t)(KB) * 64;                  \
    char* l_ = (char*)lds_b[RG] + tid * 16;                    \
    load16_lds(g_, l_);                                        \
    load16_lds(g_ + (1u << 20), l_ + 8192);                    \
} while (0)

#define VM8 asm volatile("s_waitcnt vmcnt(8)" ::: "memory")
#define VM4 asm volatile("s_waitcnt vmcnt(4)" ::: "memory")
#define VM0 asm volatile("s_waitcnt vmcnt(0)" ::: "memory")
#define VM_NONE ((void)0)

// H_: acc half for MFMA(P). MAV_/MBV_: frag sets consumed by MFMA(P).
// RAV_/RBV_: sets written by reads for P+1, from A region ARG_ half AH_
// (+ B region BRG_ if DOB_). RDC_: issue reads at all. VMW_ before barrier.
#define PHASE(H_, MAV_, MBV_, RAV_, RBV_, ARG_, AH_, DOB_, BRG_, RDC_, VMW_, STG_) do { \
    if (RDC_) {                                                                      \
        const short* Ar_ = &lds_a[ARG_][a_off + (AH_) * 2048];                       \
        _Pragma("unroll")                                                            \
        for (int f_ = 0; f_ < 4; ++f_)                                               \
            av[RAV_][f_] = *(const short8*)(Ar_ + f_ * 512);                         \
        if (DOB_) {                                                                  \
            const short* Br_ = &lds_b[BRG_][b_off];                                  \
            _Pragma("unroll")                                                        \
            for (int n_ = 0; n_ < 4; ++n_)                                           \
                bv[RBV_][n_] = *(const short8*)(Br_ + n_ * 512);                     \
        }                                                                            \
    }                                                                                \
    STG_;                                                                            \
    __builtin_amdgcn_s_setprio(1);                                                   \
    _Pragma("unroll")                                                                \
    for (int f_ = 0; f_ < 4; ++f_)                                                   \
        _Pragma("unroll")                                                            \
        for (int n_ = 0; n_ < 4; ++n_)                                               \
            acc[(H_) * 4 + f_][n_] = __builtin_amdgcn_mfma_f32_16x16x32_bf16(        \
                av[MAV_][f_], bv[MBV_][n_], acc[(H_) * 4 + f_][n_], 0, 0, 0);        \
    __builtin_amdgcn_s_setprio(0);                                                   \
    VMW_;                                                                            \
    asm volatile("s_barrier" ::: "memory");                                          \
} while (0)

__global__ __launch_bounds__(512, 2)
void gemm_kernel(const unsigned short* __restrict__ X,   // [M][K] bf16
                 const unsigned short* __restrict__ Wt,  // [N][K] bf16
                 float* __restrict__ C) {                // [M][N] f32
    __shared__ __align__(16) short lds_a[4][8192];   // 4 x 16KB regions (buf*2+ksub)
    __shared__ __align__(16) short lds_b[4][8192];   // total 128 KiB

    const int tid  = threadIdx.x;
    const int wave = tid >> 6;
    const int lane = tid & 63;
    const int wm   = wave >> 2;        // 0..1  (M)
    const int wn   = wave & 3;         // 0..3  (N)

    // XCD swizzle: 688 blocks = 8 * 86; m-fast within each XCD chunk
    // (16 consecutive blocks share one 2MB Wt panel in the XCD's L2).
    const int pid    = blockIdx.x;
    const int L      = (pid & 7) * 86 + (pid >> 3);
    const int m_tile = L & 15;          // [0,16)
    const int n_tile = L >> 4;          // [0,43)
    const int m0 = m_tile * 256;
    const int n0 = n_tile * 256;

    // staging source: thread t fills LDS region rows (t>>2) and (t>>2)+128,
    // chunk position t&3. Pre-swizzled global chunk: cl = (t&3) ^ ((row>>1)&3).
    const int row_l = tid >> 2;
    const int cl    = (tid & 3) ^ ((tid >> 3) & 3);
    const char* ApS = (const char*)X  + ((size_t)(m0 + row_l) << 13) + (cl << 4);
    const char* BpS = (const char*)Wt + ((size_t)(n0 + row_l) << 13) + (cl << 4);

    // frag read offsets (in shorts); swizzled chunk index is per-lane constant.
    const int l15 = lane & 15;
    const int kcs = (lane >> 4) ^ ((lane >> 1) & 3);
    const int a_off = (wm * 128 + l15) * 32 + kcs * 8;
    const int b_off = (wn * 64  + l15) * 32 + kcs * 8;

    floatx4 acc[8][4] = {};
    short8 av[2][4], bv[2][4];

    // prologue: stage tile0 (B0,A0,B1,A1) + tile1 (B2,A2,B3) = 14 loads.
    // vmcnt(10) -> loads 1-4 (B-RG0, A-RG0) landed before the initial frag reads.
    STAGE_B(0, 0); STAGE_A(0, 0);
    STAGE_B(1, 1); STAGE_A(1, 1);
    STAGE_B(2, 2); STAGE_A(2, 2);
    STAGE_B(3, 3);
    asm volatile("s_waitcnt vmcnt(10)" ::: "memory");
    asm volatile("s_barrier" ::: "memory");
    {
        const short* Ar = &lds_a[0][a_off];
        const short* Br = &lds_b[0][b_off];
#pragma unroll
        for (int f = 0; f < 4; ++f) av[0][f] = *(const short8*)(Ar + f * 512);
#pragma unroll
        for (int n = 0; n < 4; ++n) bv[0][n] = *(const short8*)(Br + n * 512);
    }

#pragma unroll 1
    for (int i = 0; i < NIT; ++i) {
        const int  kb4  = 4 * i;
        const bool more = (i + 1 < NIT);
        // phase P: MFMA region/half | reads for P+1        | stage        | wait
        // p1: RG0 h0 (av0,bv0)      | A(RG0,h1)->av1       | A(k+3)->A3   | VM8
        // p2: RG0 h1 (av1,bv0)      | A(RG1,h0)->av0,B1->bv1| B(k+4)->B0  | -
        // p3: RG1 h0 (av0,bv1)      | A(RG1,h1)->av1       | A(k+4)->A0   | VM8/VM4
        // p4: RG1 h1 (av1,bv1)      | A(RG2,h0)->av0,B2->bv0| B(k+5)->B1  | -
        // p5: RG2 h0 (av0,bv0)      | A(RG2,h1)->av1       | A(k+5)->A1   | VM8/VM0
        // p6: RG2 h1 (av1,bv0)      | A(RG3,h0)->av0,B3->bv1| B(k+6)->B2  | -
        // p7: RG3 h0 (av0,bv1)      | A(RG3,h1)->av1       | A(k+6)->A2   | VM8/skip
        // p8: RG3 h1 (av1,bv1)      | A(RG0',h0)->av0,B0'->bv0| B(k+7)->B3| -
        PHASE(0, 0, 0, 1, 0, 0, 1, 0, 0, 1,    VM8,                      STAGE_A(kb4 + 3, 3));
        PHASE(1, 1, 0, 0, 1, 1, 0, 1, 1, 1,    VM_NONE,                  if (more) STAGE_B(kb4 + 4, 0));
        PHASE(0, 0, 1, 1, 0, 1, 1, 0, 0, 1,    if (more) VM8; else VM4,  if (more) STAGE_A(kb4 + 4, 0));
        PHASE(1, 1, 1, 0, 0, 2, 0, 1, 2, 1,    VM_NONE,                  if (more) STAGE_B(kb4 + 5, 1));
        PHASE(0, 0, 0, 1, 0, 2, 1, 0, 0, 1,    if (more) VM8; else VM0,  if (more) STAGE_A(kb4 + 5, 1));
        PHASE(1, 1, 0, 0, 1, 3, 0, 1, 3, 1,    VM_NONE,                  if (more) STAGE_B(kb4 + 6, 2));
        PHASE(0, 0, 1, 1, 0, 3, 1, 0, 0, 1,    if (more) VM8,            if (more) STAGE_A(kb4 + 6, 2));
        PHASE(1, 1, 1, 0, 0, 0, 0, 1, 0, more, VM_NONE,                  if (more) STAGE_B(kb4 + 7, 3));
    }

    // epilogue: C/D layout col=lane&15, row=(lane>>4)*4+reg  [verified m89/m91]
    // nontemporal: C is write-once, never re-read.
    const int crow = (lane >> 4) * 4;
#pragma unroll
    for (int f = 0; f < 8; ++f) {
#pragma unroll
        for (int n = 0; n < 4; ++n) {
            float* Cp = C + (size_t)(m0 + wm * 128 + f * 16 + crow) * N_DIM
                          + (n0 + wn * 64 + n * 16 + l15);
#pragma unroll
            for (int r = 0; r < 4; ++r)
                __builtin_nontemporal_store(acc[f][n][r], Cp + (size_t)r * N_DIM);
        }
    }
}

// ---------------------------------------------------------------------------
extern "C" void kernel_launch(void* const* d_in, const int* in_sizes, int n_in,
                              void* d_out, int out_size, void* d_ws, size_t ws_size,
                              hipStream_t stream) {
    const float* x       = (const float*)d_in[0];
    const int*   qweight = (const int*)d_in[1];
    const float* scales  = (const float*)d_in[2];
    const int*   qzeros  = (const int*)d_in[3];
    // d_in[4] = group_size scalar (always 128 per setup_inputs) -- baked in.
    float* out = (float*)d_out;

    // ws layout: Xb bf16 [M][K] (33.5 MB) | Wt bf16 [N][K] (90.2 MB)
    unsigned short* Xb = (unsigned short*)d_ws;
    unsigned short* Wt = (unsigned short*)((char*)d_ws + (size_t)M_DIM * K_DIM * 2);

    convert_x_kernel<<<(M_DIM * K_DIM) / (256 * 8), 256, 0, stream>>>(x, Xb);
    dequant_kernel<<<dim3(N_DIM / 256, K_DIM / 64), 256, 0, stream>>>(qweight, scales, qzeros, Wt);
    gemm_kernel<<<(M_DIM / 256) * (N_DIM / 256), 512, 0, stream>>>(Xb, Wt, out);
}

// Round 4
// 594.428 us; speedup vs baseline: 1.2162x; 1.0324x over previous
//
#include <hip/hip_runtime.h>
#include <hip/hip_bf16.h>
#include <stdint.h>

// Problem constants: x[4096,4096] f32, qweight[4096,1376] i32,
// scales[32,11008] f32, qzeros[32,1376] i32, group_size=128. out[4096,11008] f32.
#define M_DIM 4096
#define K_DIM 4096
#define N_DIM 11008
#define OPACK (N_DIM / 8)   // 1376
#define GSZ   128

// GEMM geometry: 256x256 block tile, BK=64 (2 ksubs of 32), 8 waves (2M x 4N),
// 512 threads, 8-phase K-loop, 2 K-tiles per iteration.
#define NIT 32              // K / 128

typedef __attribute__((ext_vector_type(8))) short short8;        // 8 bf16 (MFMA A/B frag)
typedef __attribute__((ext_vector_type(4))) float floatx4;       // MFMA C/D frag
typedef __attribute__((ext_vector_type(4))) unsigned int uintx4; // 16B vector

static __device__ __forceinline__ unsigned short f32_to_bf16_rne(float f) {
    union { float f; unsigned int u; } c; c.f = f;
    unsigned int u = c.u;
    u += 0x7fffu + ((u >> 16) & 1u);   // round-to-nearest-even (no NaN inputs here)
    return (unsigned short)(u >> 16);
}

// async global->LDS, 16B per lane. LDS dest must be wave-uniform base + lane*16.
static __device__ __forceinline__ void load16_lds(const void* gptr, void* lptr) {
    __builtin_amdgcn_global_load_lds(
        (__attribute__((address_space(1))) void*)gptr,
        (__attribute__((address_space(3))) void*)lptr,
        16, 0, 0);
}

// ---------------------------------------------------------------------------
// Kernel 1: x fp32 [M][K] -> bf16 (row-major, same layout)
// ---------------------------------------------------------------------------
__global__ __launch_bounds__(256)
void convert_x_kernel(const float* __restrict__ x, unsigned short* __restrict__ xb) {
    const int idx = (blockIdx.x * 256 + threadIdx.x) * 8;
    floatx4 v0 = *(const floatx4*)(x + idx);
    floatx4 v1 = *(const floatx4*)(x + idx + 4);
    unsigned short r[8];
#pragma unroll
    for (int i = 0; i < 4; i++) {
        r[i]     = f32_to_bf16_rne(v0[i]);
        r[4 + i] = f32_to_bf16_rne(v1[i]);
    }
    *(uintx4*)(xb + idx) = *(const uintx4*)r;
}

// ---------------------------------------------------------------------------
// Kernel 2: dequant int4 -> bf16 transposed, Wt[o][i].
// LDS-staged coalesced writes (round 6): compute into LDS tile [256 o][64 i]
// with XOR-swizzled 16B chunks, then write out wave-coalesced (8 full 128B
// lines per wave-store). Measured: ~34us faster than direct scattered stores.
// ---------------------------------------------------------------------------
__global__ __launch_bounds__(256)
void dequant_kernel(const int* __restrict__ qweight, const float* __restrict__ scales,
                    const int* __restrict__ qzeros, unsigned short* __restrict__ Wt) {
    __shared__ __align__(16) unsigned short tile[256][64];   // 32 KB

    const int tid = threadIdx.x;
    const int o0  = blockIdx.x * 256;
    const int i0  = blockIdx.y * 64;                 // one scale group spans >=64 i
    const int o   = o0 + tid;
    const int g   = i0 >> 7;
    const int op  = o >> 3;
    const int sh  = (o & 7) * 4;
    const int z   = (qzeros[g * OPACK + op] >> sh) & 15;
    const float s = scales[g * N_DIM + o];

    unsigned short buf[64];
#pragma unroll
    for (int k = 0; k < 64; k++) {
        const int q   = qweight[(i0 + k) * OPACK + op];
        const float w = (float)(((q >> sh) & 15) - z) * s;
        buf[k] = f32_to_bf16_rne(w);
    }
    // stage into LDS row tid, chunk c stored at slot c ^ (tid&7)
#pragma unroll
    for (int c = 0; c < 8; c++)
        *(uintx4*)&tile[tid][(c ^ (tid & 7)) * 8] = *(const uintx4*)&buf[c * 8];

    __syncthreads();

    // write out: iteration j covers rows (tid>>3) + 32j; lanes 0..7 cover the
    // 8 chunks of one row -> each wave-store = 8 full 128B lines.
    const int c_out = tid & 7;
#pragma unroll
    for (int j = 0; j < 8; j++) {
        const int r = (tid >> 3) + j * 32;
        const uintx4 v = *(const uintx4*)&tile[r][(c_out ^ (r & 7)) * 8];
        *(uintx4*)&Wt[(size_t)(o0 + r) * K_DIM + i0 + c_out * 8] = v;
    }
}

// ---------------------------------------------------------------------------
// Kernel 3: C[M][N] f32 = Xb[M][K] (bf16) @ Wt[N][K]^T (bf16)
// ROUND 7: drain-free counted-vmcnt pipeline.
//   Post-mortem r4-r6: phase time ~1350cy vs ~300cy of work. Root cause: every
//   waitcnt/barrier asm carried ::: "memory" -- LLVM's waitcnt pass treats
//   may-read-memory asm as a consumer of outstanding global_load_lds (LDS-DMA)
//   and inserts s_waitcnt vmcnt(0) before it => the staging queue drained EVERY
//   phase; the counted-vmcnt ledger was dead code; one exposed L2/L3 round trip
//   (~600-900cy) per phase. Matches the schedule-insensitivity of r4-r6.
//   Fix (this round's ONLY gemm change):
//     - barriers: __builtin_amdgcn_s_barrier() (no fence, no drain)
//     - waits: bare asm "s_waitcnt vmcnt(N)" WITHOUT memory clobber
//     - compiler-motion safety: sched_barrier(0) fences (free at runtime)
//   Phase P: { setprio(1) 16xMFMA setprio(0) | [VM] | reads(P+1)->other set |
//              stage | s_barrier }
//   vmcnt ledger (re-derived, in-order retirement per m135): 1 unit (2 loads)
//   staged per phase. VM6 at p1/p3/p5/p7 (post-MFMA, PRE-reads): outstanding
//   pre-wait = units {P-4..P-1} = 8 loads, VM6 lands unit P-4 => landed set
//   = stages <= P-4. Read needs (stage distances): p2:A-R1(p5-),B-R1(p4-);
//   p4:A-R2(p7-),B-R2(p6-); p6:A-R3(p1),B-R3(p8-); p8:A-R0'(p3),B-R0'(p2).
//   p1-VM6 -> <=p5-prev; p3-VM6 -> <=p7-prev; p5-VM6 -> <=p1; p7-VM6 -> <=p3.
//   All covered (tight). Last iter: p3->VM4, p5->VM0, p7->skip (p8 reads none).
//   WAR: region last-read at P lgkm-retires before P+1's MFMA (pre-P+1-barrier);
//   overwriting stage at >=P+2 is post-P+1-barrier => >=1 barrier between. Sound.
//   T2 swizzle (0 conflicts measured), T5 setprio, T1 XCD swizzle retained.
// ---------------------------------------------------------------------------

#define STAGE_A(KB, RG) do {                                   \
    const char* g_ = ApS + (size_t)(KB) * 64;                  \
    char* l_ = (char*)lds_a[RG] + tid * 16;                    \
    load16_lds(g_, l_);                                        \
    load16_lds(g_ + (1u << 20), l_ + 8192);                    \
} while (0)

#define STAGE_B(KB, RG) do {                                   \
    const char* g_ = BpS + (size_t)(KB) * 64;                  \
    char* l_ = (char*)lds_b[RG] + tid * 16;                    \
    load16_lds(g_, l_);                                        \
    load16_lds(g_ + (1u << 20), l_ + 8192);                    \
} while (0)

// bare counted waits -- NO memory clobber (a clobber forces vmcnt(0) drain)
#define VM6 asm volatile("s_waitcnt vmcnt(6)")
#define VM4 asm volatile("s_waitcnt vmcnt(4)")
#define VM0 asm volatile("s_waitcnt vmcnt(0)")
#define VM_NONE ((void)0)

// H_: acc half for MFMA(P). MAV_/MBV_: frag sets consumed by MFMA(P).
// RAV_/RBV_: sets written by reads for P+1 from A region ARG_ half AH_
// (+ B region BRG_ if DOB_). RDC_: issue reads at all. VMW_: wait (pre-reads).
#define PHASE(H_, MAV_, MBV_, RAV_, RBV_, ARG_, AH_, DOB_, BRG_, RDC_, VMW_, STG_) do { \
    __builtin_amdgcn_s_setprio(1);                                                   \
    _Pragma("unroll")                                                                \
    for (int f_ = 0; f_ < 4; ++f_)                                                   \
        _Pragma("unroll")                                                            \
        for (int n_ = 0; n_ < 4; ++n_)                                               \
            acc[(H_) * 4 + f_][n_] = __builtin_amdgcn_mfma_f32_16x16x32_bf16(        \
                av[MAV_][f_], bv[MBV_][n_], acc[(H_) * 4 + f_][n_], 0, 0, 0);        \
    __builtin_amdgcn_s_setprio(0);                                                   \
    VMW_;                                                                            \
    __builtin_amdgcn_sched_barrier(0);                                               \
    if (RDC_) {                                                                      \
        const short* Ar_ = &lds_a[ARG_][a_off + (AH_) * 2048];                       \
        _Pragma("unroll")                                                            \
        for (int f_ = 0; f_ < 4; ++f_)                                               \
            av[RAV_][f_] = *(const short8*)(Ar_ + f_ * 512);                         \
        if (DOB_) {                                                                  \
            const short* Br_ = &lds_b[BRG_][b_off];                                  \
            _Pragma("unroll")                                                        \
            for (int n_ = 0; n_ < 4; ++n_)                                           \
                bv[RBV_][n_] = *(const short8*)(Br_ + n_ * 512);                     \
        }                                                                            \
    }                                                                                \
    STG_;                                                                            \
    __builtin_amdgcn_sched_barrier(0);                                               \
    __builtin_amdgcn_s_barrier();                                                    \
    __builtin_amdgcn_sched_barrier(0);                                               \
} while (0)

__global__ __launch_bounds__(512, 2)
void gemm_kernel(const unsigned short* __restrict__ X,   // [M][K] bf16
                 const unsigned short* __restrict__ Wt,  // [N][K] bf16
                 float* __restrict__ C) {                // [M][N] f32
    __shared__ __align__(16) short lds_a[4][8192];   // 4 x 16KB regions (buf*2+ksub)
    __shared__ __align__(16) short lds_b[4][8192];   // total 128 KiB

    const int tid  = threadIdx.x;
    const int wave = tid >> 6;
    const int lane = tid & 63;
    const int wm   = wave >> 2;        // 0..1  (M)
    const int wn   = wave & 3;         // 0..3  (N)

    // XCD swizzle: 688 blocks = 8 * 86; m-fast within each XCD chunk
    // (16 consecutive blocks share one 2MB Wt panel in the XCD's L2).
    const int pid    = blockIdx.x;
    const int L      = (pid & 7) * 86 + (pid >> 3);
    const int m_tile = L & 15;          // [0,16)
    const int n_tile = L >> 4;          // [0,43)
    const int m0 = m_tile * 256;
    const int n0 = n_tile * 256;

    // staging source: thread t fills LDS region rows (t>>2) and (t>>2)+128,
    // chunk position t&3. Pre-swizzled global chunk: cl = (t&3) ^ ((row>>1)&3).
    const int row_l = tid >> 2;
    const int cl    = (tid & 3) ^ ((tid >> 3) & 3);
    const char* ApS = (const char*)X  + ((size_t)(m0 + row_l) << 13) + (cl << 4);
    const char* BpS = (const char*)Wt + ((size_t)(n0 + row_l) << 13) + (cl << 4);

    // frag read offsets (in shorts); swizzled chunk index is per-lane constant.
    const int l15 = lane & 15;
    const int kcs = (lane >> 4) ^ ((lane >> 1) & 3);
    const int a_off = (wm * 128 + l15) * 32 + kcs * 8;
    const int b_off = (wn * 64  + l15) * 32 + kcs * 8;

    floatx4 acc[8][4] = {};
    short8 av[2][4], bv[2][4];

    // prologue: stage tile0 (B0,A0,B1,A1) + tile1 (B2,A2,B3) = 14 loads.
    // (A-R3 of tile1 is staged at p1 of iter 0 -- consistent with steady state.)
    // vmcnt(10) -> units B0,A0 landed for the initial frag reads.
    STAGE_B(0, 0); STAGE_A(0, 0);
    STAGE_B(1, 1); STAGE_A(1, 1);
    STAGE_B(2, 2); STAGE_A(2, 2);
    STAGE_B(3, 3);
    asm volatile("s_waitcnt vmcnt(10)");
    __builtin_amdgcn_sched_barrier(0);
    __builtin_amdgcn_s_barrier();
    __builtin_amdgcn_sched_barrier(0);
    {
        const short* Ar = &lds_a[0][a_off];
        const short* Br = &lds_b[0][b_off];
#pragma unroll
        for (int f = 0; f < 4; ++f) av[0][f] = *(const short8*)(Ar + f * 512);
#pragma unroll
        for (int n = 0; n < 4; ++n) bv[0][n] = *(const short8*)(Br + n * 512);
    }

#pragma unroll 1
    for (int i = 0; i < NIT; ++i) {
        const int  kb4  = 4 * i;
        const bool more = (i + 1 < NIT);
        // phase P: MFMA region/half      | reads for P+1           | stage (slot)
        // p1: R0 h0 (av0,bv0)            | A(R0,h1)->av1           | A(k+3)->A-R3
        // p2: R0 h1 (av1,bv0)            | A(R1,h0)->av0, B1->bv1  | B(k+4)->B-R0
        // p3: R1 h0 (av0,bv1)            | A(R1,h1)->av1           | A(k+4)->A-R0
        // p4: R1 h1 (av1,bv1)            | A(R2,h0)->av0, B2->bv0  | B(k+5)->B-R1
        // p5: R2 h0 (av0,bv0)            | A(R2,h1)->av1           | A(k+5)->A-R1
        // p6: R2 h1 (av1,bv0)            | A(R3,h0)->av0, B3->bv1  | B(k+6)->B-R2
        // p7: R3 h0 (av0,bv1)            | A(R3,h1)->av1           | A(k+6)->A-R2
        // p8: R3 h1 (av1,bv1)            | A(R0',h0)->av0,B0'->bv0 | B(k+7)->B-R3
        PHASE(0, 0, 0, 1, 0, 0, 1, 0, 0, 1,    VM6,                      STAGE_A(kb4 + 3, 3));
        PHASE(1, 1, 0, 0, 1, 1, 0, 1, 1, 1,    VM_NONE,                  if (more) STAGE_B(kb4 + 4, 0));
        PHASE(0, 0, 1, 1, 0, 1, 1, 0, 0, 1,    if (more) VM6; else VM4,  if (more) STAGE_A(kb4 + 4, 0));
        PHASE(1, 1, 1, 0, 0, 2, 0, 1, 2, 1,    VM_NONE,                  if (more) STAGE_B(kb4 + 5, 1));
        PHASE(0, 0, 0, 1, 0, 2, 1, 0, 0, 1,    if (more) VM6; else VM0,  if (more) STAGE_A(kb4 + 5, 1));
        PHASE(1, 1, 0, 0, 1, 3, 0, 1, 3, 1,    VM_NONE,                  if (more) STAGE_B(kb4 + 6, 2));
        PHASE(0, 0, 1, 1, 0, 3, 1, 0, 0, 1,    if (more) VM6; else VM_NONE, if (more) STAGE_A(kb4 + 6, 2));
        PHASE(1, 1, 1, 0, 0, 0, 0, 1, 0, more, VM_NONE,                  if (more) STAGE_B(kb4 + 7, 3));
    }

    // epilogue: C/D layout col=lane&15, row=(lane>>4)*4+reg  [verified m89/m91]
    // nontemporal: C is write-once, never re-read.
    const int crow = (lane >> 4) * 4;
#pragma unroll
    for (int f = 0; f < 8; ++f) {
#pragma unroll
        for (int n = 0; n < 4; ++n) {
            float* Cp = C + (size_t)(m0 + wm * 128 + f * 16 + crow) * N_DIM
                          + (n0 + wn * 64 + n * 16 + l15);
#pragma unroll
            for (int r = 0; r < 4; ++r)
                __builtin_nontemporal_store(acc[f][n][r], Cp + (size_t)r * N_DIM);
        }
    }
}

// ---------------------------------------------------------------------------
extern "C" void kernel_launch(void* const* d_in, const int* in_sizes, int n_in,
                              void* d_out, int out_size, void* d_ws, size_t ws_size,
                              hipStream_t stream) {
    const float* x       = (const float*)d_in[0];
    const int*   qweight = (const int*)d_in[1];
    const float* scales  = (const float*)d_in[2];
    const int*   qzeros  = (const int*)d_in[3];
    // d_in[4] = group_size scalar (always 128 per setup_inputs) -- baked in.
    float* out = (float*)d_out;

    // ws layout: Xb bf16 [M][K] (33.5 MB) | Wt bf16 [N][K] (90.2 MB)
    unsigned short* Xb = (unsigned short*)d_ws;
    unsigned short* Wt = (unsigned short*)((char*)d_ws + (size_t)M_DIM * K_DIM * 2);

    convert_x_kernel<<<(M_DIM * K_DIM) / (256 * 8), 256, 0, stream>>>(x, Xb);
    dequant_kernel<<<dim3(N_DIM / 256, K_DIM / 64), 256, 0, stream>>>(qweight, scales, qzeros, Wt);
    gemm_kernel<<<(M_DIM / 256) * (N_DIM / 256), 512, 0, stream>>>(Xb, Wt, out);
}